// Round 3
// baseline (960.122 us; speedup 1.0000x reference)
//
#include <hip/hip_runtime.h>
#include <math.h>

#define T 8
#define NI 20000
#define NK 50000
#define F 128
#define H 256
#define O 128
#define E 500000
#define G3 (3*H)          // 768
#define MAXS 256          // slot cap per timestep (E[slots]=25)
#define BMW 1568          // ceil(NK/32)
#define NB 8              // persistent blocks
#define RPB 32            // h-indices per block (H/NB)
#define NPHASE 10         // 1 hitem + 1 gi + 8 GRU steps

// ---------------- workspace layout (bytes) ----------------
#define OFF_CNT2   0                          // T ints
#define OFF_ITEMS  32                         // T*MAXS ints
#define OFF_CNT1   (OFF_ITEMS + T*MAXS*4)
#define OFF_SUMX2  (OFF_CNT1 + T*MAXS*4)      // T*F floats
#define OFF_HSUM   (OFF_SUMX2 + T*F*4)        // T*H floats
#define OFF_GI     (OFF_HSUM + T*H*4)         // T*G3 floats
#define OFF_RNN    (OFF_GI + T*G3*4)          // T*H floats
#define OFF_FLAGS  (OFF_RNN + T*H*4)          // NPHASE*NB*16 ints (64B-strided flags)
#define OFF_SUM1   (OFF_FLAGS + NPHASE*NB*16*4)
#define WS_USED    (OFF_SUM1 + (size_t)T*MAXS*F*4)

// K1: scan e2_dst (int4) for edges into target; record src items (slots) and
// accumulate per-edge x_item[src] into sum_x2 (h_inf mean numerator).
__global__ void k_find_e2(const int* __restrict__ e2_src, const int* __restrict__ e2_dst,
                          const float* __restrict__ x_item, const int* __restrict__ target_p,
                          int* __restrict__ cnt2, int* __restrict__ items,
                          float* __restrict__ sum_x2) {
    int t = blockIdx.y;
    long q = (long)blockIdx.x * 256 + threadIdx.x;
    if (q >= E / 4) return;
    int target = *target_p;
    int4 d4 = ((const int4*)(e2_dst + (long)t * E))[q];
    int dv[4] = {d4.x, d4.y, d4.z, d4.w};
    #pragma unroll
    for (int c = 0; c < 4; ++c) {
        if (dv[c] == target) {
            long j = q * 4 + c;
            int src = e2_src[(long)t * E + j];
            int pos = atomicAdd(&cnt2[t], 1);
            if (pos < MAXS) items[t * MAXS + pos] = src;
            const float* xr = x_item + ((long)t * NK + src) * F;
            float* acc = sum_x2 + t * F;
            for (int f = 0; f < F; ++f) atomicAdd(&acc[f], xr[f]);
        }
    }
}

// K2: scan e1_dst (int4); accumulate x_inf[src] into matching item slot.
__global__ void k_scan_e1(const int* __restrict__ e1_src, const int* __restrict__ e1_dst,
                          const float* __restrict__ x_inf,
                          const int* __restrict__ cnt2, const int* __restrict__ items,
                          int* __restrict__ cnt1, float* __restrict__ sum1) {
    __shared__ int s_items[MAXS];
    __shared__ unsigned s_bm[BMW];
    int t = blockIdx.y;
    int ns = min(cnt2[t], MAXS);
    for (int i = threadIdx.x; i < BMW; i += 256) s_bm[i] = 0u;
    __syncthreads();
    for (int i = threadIdx.x; i < ns; i += 256) {
        int it = items[t * MAXS + i];
        s_items[i] = it;
        atomicOr(&s_bm[it >> 5], 1u << (it & 31));
    }
    __syncthreads();
    long q = (long)blockIdx.x * 256 + threadIdx.x;
    if (q >= E / 4) return;
    int4 d4 = ((const int4*)(e1_dst + (long)t * E))[q];
    int dv[4] = {d4.x, d4.y, d4.z, d4.w};
    #pragma unroll
    for (int c = 0; c < 4; ++c) {
        int d = dv[c];
        if (!((s_bm[d >> 5] >> (d & 31)) & 1u)) continue;
        int src = e1_src[(long)t * E + q * 4 + c];
        const float* xr = x_inf + ((long)t * NI + src) * F;
        for (int i = 0; i < ns; ++i) {
            if (s_items[i] == d) {
                atomicAdd(&cnt1[t * MAXS + i], 1);
                float* acc = sum1 + ((long)t * MAXS + i) * F;
                for (int f = 0; f < F; ++f) atomicAdd(&acc[f], xr[f]);
            }
        }
    }
}

// device-wide barrier over NB co-resident blocks: per-block release flag on its
// own 64B line; lanes 0..NB-1 each poll one flag (no RMW serialization).
__device__ __forceinline__ void flag_barrier(int* flags, int phase, int b) {
    __syncthreads();
    int tid = threadIdx.x;
    if (tid == 0) {
        __threadfence();
        __hip_atomic_store(&flags[(phase * NB + b) * 16], 1, __ATOMIC_RELEASE,
                           __HIP_MEMORY_SCOPE_AGENT);
    }
    if (tid < NB) {
        while (__hip_atomic_load(&flags[(phase * NB + tid) * 16], __ATOMIC_ACQUIRE,
                                 __HIP_MEMORY_SCOPE_AGENT) == 0)
            __builtin_amdgcn_s_sleep(1);
        __threadfence();
    }
    __syncthreads();
}

// K3: persistent 8-block fused kernel.
//  phase A: h_item for slots (slot % NB == b), atomicAdd into hsum
//  phase B: block t: h_inf[target] -> o[t] (LDS-local) -> gi[t] (global)
//  phase C: GRU, block b owns h[32b..32b+32), W_hh slice in LDS
//  tail   : block 0: attention + prediction head
__global__ void __launch_bounds__(256, 1)
k_fused(const float* __restrict__ x_item, const float* __restrict__ x_inf,
        const int* __restrict__ target_p,
        const float* __restrict__ W1a_l, const float* __restrict__ b1a_l,
        const float* __restrict__ W1a_r,
        const float* __restrict__ W1b_l, const float* __restrict__ b1b_l,
        const float* __restrict__ W1b_r,
        const float* __restrict__ W2b_l, const float* __restrict__ b2b_l,
        const float* __restrict__ W2b_r,
        const float* __restrict__ W_ih, const float* __restrict__ b_ih,
        const float* __restrict__ W_hh, const float* __restrict__ b_hh,
        const float* __restrict__ W_att, const float* __restrict__ b_att,
        const float* __restrict__ W_p1, const float* __restrict__ b_p1,
        const float* __restrict__ W_p2, const float* __restrict__ b_p2,
        const int* __restrict__ cnt2, const int* __restrict__ items,
        const int* __restrict__ cnt1, const float* __restrict__ sum_x2,
        const float* __restrict__ sum1,
        float* __restrict__ hsum, float* __restrict__ gi, float* __restrict__ rnn,
        int* __restrict__ flags, float* __restrict__ out) {
    __shared__ float w[3 * RPB][H];   // 96 KiB: this block's W_hh rows
    __shared__ float z1[F], xk[F];
    __shared__ float hvec[H];
    __shared__ float srnn[T][H];
    __shared__ float satt[T], tmp[H], hid[H / 2];
    int b = blockIdx.x, tid = threadIdx.x;

    // start W_hh slice load first (no dependency; overlaps phase A)
    for (int idx = tid; idx < 3 * RPB * H; idx += 256) {
        int r = idx >> 8, k = idx & 255;
        int g = r / RPB, j = r - g * RPB;
        w[r][k] = W_hh[((long)(g * H + b * RPB + j)) * H + k];
    }

    // ---- phase A: h_item slots ----
    for (int t = 0; t < T; ++t) {
        int ns = min(cnt2[t], MAXS);
        for (int s = b; s < ns; s += NB) {
            __syncthreads();
            if (tid < F) {
                int item = items[t * MAXS + s];
                float inv = 1.0f / fmaxf((float)cnt1[t * MAXS + s], 1.0f);
                z1[tid] = sum1[((long)t * MAXS + s) * F + tid] * inv;
                xk[tid] = x_item[((long)t * NK + item) * F + tid];
            }
            __syncthreads();
            float acc = b1a_l[tid];
            const float* wl = W1a_l + tid * F;
            const float* wr = W1a_r + tid * F;
            for (int f = 0; f < F; ++f) acc += z1[f] * wl[f] + xk[f] * wr[f];
            atomicAdd(&hsum[t * H + tid], fmaxf(acc, 0.0f));
        }
    }
    flag_barrier(flags, 0, b);

    // ---- phase B: layer2 + gi for t = b ----
    {
        int t = b;
        int target = *target_p;
        float c2 = fmaxf((float)cnt2[t], 1.0f);
        __syncthreads();
        if (tid < F) {
            z1[tid] = sum_x2[t * F + tid] / c2;
            xk[tid] = x_inf[((long)t * NI + target) * F + tid];
        }
        __syncthreads();
        float acc = b1b_l[tid];
        {
            const float* wl = W1b_l + tid * F;
            const float* wr = W1b_r + tid * F;
            for (int f = 0; f < F; ++f) acc += z1[f] * wl[f] + xk[f] * wr[f];
        }
        hvec[tid] = fmaxf(acc, 0.0f);        // h_inf[target]
        tmp[tid] = hsum[t * H + tid] / c2;   // mean h_item
        __syncthreads();
        if (tid < O) {
            float a = b2b_l[tid];
            const float* wl = W2b_l + tid * H;
            const float* wr = W2b_r + tid * H;
            for (int k = 0; k < H; ++k) a += tmp[k] * wl[k] + hvec[k] * wr[k];
            z1[tid] = a;                     // o[t], LDS-local
        }
        __syncthreads();
        for (int r = 0; r < 3; ++r) {        // gi rows: 3 per thread
            int row = tid + r * 256;
            float a = b_ih[row];
            const float* wi = W_ih + (long)row * O;
            for (int k = 0; k < O; ++k) a += wi[k] * z1[k];
            __hip_atomic_store(&gi[t * G3 + row], a, __ATOMIC_RELAXED,
                               __HIP_MEMORY_SCOPE_AGENT);
        }
    }
    flag_barrier(flags, 1, b);

    // ---- phase C: GRU ----
    hvec[tid] = 0.0f;
    __syncthreads();
    int wv = tid >> 6, lane = tid & 63;
    for (int t = 0; t < T; ++t) {
        for (int j = wv; j < RPB; j += 4) {
            float sr = 0.f, sz = 0.f, sn = 0.f;
            for (int c = 0; c < 4; ++c) {
                int k = lane + 64 * c;
                float hk = hvec[k];
                sr += w[j][k] * hk;
                sz += w[RPB + j][k] * hk;
                sn += w[2 * RPB + j][k] * hk;
            }
            for (int off = 32; off; off >>= 1) {
                sr += __shfl_down(sr, off);
                sz += __shfl_down(sz, off);
                sn += __shfl_down(sn, off);
            }
            if (lane == 0) {
                int i = b * RPB + j;
                float gir = __hip_atomic_load(&gi[t * G3 + i], __ATOMIC_RELAXED,
                                              __HIP_MEMORY_SCOPE_AGENT);
                float giz = __hip_atomic_load(&gi[t * G3 + H + i], __ATOMIC_RELAXED,
                                              __HIP_MEMORY_SCOPE_AGENT);
                float gin = __hip_atomic_load(&gi[t * G3 + 2 * H + i], __ATOMIC_RELAXED,
                                              __HIP_MEMORY_SCOPE_AGENT);
                float r = 1.0f / (1.0f + expf(-(gir + sr + b_hh[i])));
                float z = 1.0f / (1.0f + expf(-(giz + sz + b_hh[H + i])));
                float n = tanhf(gin + r * (sn + b_hh[2 * H + i]));
                float hn = (1.0f - z) * n + z * hvec[i];
                __hip_atomic_store(&rnn[t * H + i], hn, __ATOMIC_RELAXED,
                                   __HIP_MEMORY_SCOPE_AGENT);
            }
        }
        flag_barrier(flags, 2 + t, b);
        float hnew = __hip_atomic_load(&rnn[t * H + tid], __ATOMIC_RELAXED,
                                       __HIP_MEMORY_SCOPE_AGENT);
        hvec[tid] = hnew;
        if (b == 0) srnn[t][tid] = hnew;
        __syncthreads();
    }
    if (b != 0) return;

    // ---- tail: attention + head ----
    {   // att scores: 32 lanes per t
        int tt = tid >> 5, l32 = tid & 31;
        float a = 0.f;
        for (int c = 0; c < 8; ++c) {
            int k = l32 + 32 * c;
            a += W_att[k] * srnn[tt][k];
        }
        for (int off = 16; off; off >>= 1) a += __shfl_down(a, off, 32);
        if (l32 == 0) satt[tt] = a + b_att[0];
    }
    __syncthreads();
    if (tid == 0) {
        float m = satt[0];
        for (int t = 1; t < T; ++t) m = fmaxf(m, satt[t]);
        float s = 0.f;
        for (int t = 0; t < T; ++t) { satt[t] = expf(satt[t] - m); s += satt[t]; }
        for (int t = 0; t < T; ++t) satt[t] /= s;
    }
    __syncthreads();
    {
        float ctx = 0.f;
        for (int t = 0; t < T; ++t) ctx += satt[t] * srnn[t][tid];
        tmp[tid] = ctx;
    }
    __syncthreads();
    if (tid < H / 2) {
        float a = b_p1[tid];
        const float* wp = W_p1 + (long)tid * H;
        for (int k = 0; k < H; ++k) a += wp[k] * tmp[k];
        hid[tid] = fmaxf(a, 0.0f);
    }
    __syncthreads();
    if (tid == 0) {
        float s = b_p2[0];
        for (int k = 0; k < H / 2; ++k) s += W_p2[k] * hid[k];
        out[0] = s;
    }
}

extern "C" void kernel_launch(void* const* d_in, const int* in_sizes, int n_in,
                              void* d_out, int out_size, void* d_ws, size_t ws_size,
                              hipStream_t stream) {
    const float* x_inf  = (const float*)d_in[0];
    const float* x_item = (const float*)d_in[1];
    const int* e1_src = (const int*)d_in[2];
    const int* e1_dst = (const int*)d_in[3];
    const int* e2_src = (const int*)d_in[4];
    const int* e2_dst = (const int*)d_in[5];
    const int* target_p = (const int*)d_in[6];
    const float* W1a_l = (const float*)d_in[7];
    const float* b1a_l = (const float*)d_in[8];
    const float* W1a_r = (const float*)d_in[9];
    const float* W1b_l = (const float*)d_in[10];
    const float* b1b_l = (const float*)d_in[11];
    const float* W1b_r = (const float*)d_in[12];
    const float* W2b_l = (const float*)d_in[16];
    const float* b2b_l = (const float*)d_in[17];
    const float* W2b_r = (const float*)d_in[18];
    const float* W_ih = (const float*)d_in[19];
    const float* W_hh = (const float*)d_in[20];
    const float* b_ih = (const float*)d_in[21];
    const float* b_hh = (const float*)d_in[22];
    const float* W_att = (const float*)d_in[23];
    const float* b_att = (const float*)d_in[24];
    const float* W_p1 = (const float*)d_in[25];
    const float* b_p1 = (const float*)d_in[26];
    const float* W_p2 = (const float*)d_in[27];
    const float* b_p2 = (const float*)d_in[28];
    float* out = (float*)d_out;

    char* ws = (char*)d_ws;
    int*   cnt2   = (int*)(ws + OFF_CNT2);
    int*   items  = (int*)(ws + OFF_ITEMS);
    int*   cnt1   = (int*)(ws + OFF_CNT1);
    float* sum_x2 = (float*)(ws + OFF_SUMX2);
    float* hsum   = (float*)(ws + OFF_HSUM);
    float* gi     = (float*)(ws + OFF_GI);
    float* rnn    = (float*)(ws + OFF_RNN);
    int*   flags  = (int*)(ws + OFF_FLAGS);
    float* sum1   = (float*)(ws + OFF_SUM1);

    hipMemsetAsync(d_ws, 0, WS_USED, stream);

    dim3 g1((E / 4 + 255) / 256, T);
    k_find_e2<<<g1, 256, 0, stream>>>(e2_src, e2_dst, x_item, target_p, cnt2, items, sum_x2);
    k_scan_e1<<<g1, 256, 0, stream>>>(e1_src, e1_dst, x_inf, cnt2, items, cnt1, sum1);

    k_fused<<<NB, 256, 0, stream>>>(x_item, x_inf, target_p,
                                    W1a_l, b1a_l, W1a_r,
                                    W1b_l, b1b_l, W1b_r,
                                    W2b_l, b2b_l, W2b_r,
                                    W_ih, b_ih, W_hh, b_hh,
                                    W_att, b_att, W_p1, b_p1, W_p2, b_p2,
                                    cnt2, items, cnt1, sum_x2, sum1,
                                    hsum, gi, rnn, flags, out);
}